// Round 7
// baseline (17781.812 us; speedup 1.0000x reference)
//
#include <hip/hip_runtime.h>
#include <hip/hip_bf16.h>
#include <math.h>

__device__ __forceinline__ float u2f(unsigned short u) {
    union { unsigned int i; float f; } x; x.i = ((unsigned int)u) << 16; return x.f;
}
__device__ __forceinline__ unsigned short f2u(float f) {
    union { float f; unsigned int i; } c; c.f = f;
    unsigned int r = c.i + 0x7FFF + ((c.i >> 16) & 1);   // round-to-nearest-even
    return (unsigned short)(r >> 16);
}
__device__ __forceinline__ float gelu_exact(float x) {
    return 0.5f * x * (1.0f + erff(x * 0.7071067811865475f));
}

// ===================== Kernel A: LN1 + window attention + proj residual =====
// One block per window w = bt*32 + p (1024 blocks, 256 threads).
__global__ __launch_bounds__(256) void attn_block_k(
    const float* __restrict__ x, const float* __restrict__ mask,
    const float* __restrict__ adj,
    const float* __restrict__ g1, const float* __restrict__ be1,
    const float* __restrict__ Wqkv, const float* __restrict__ Bqkv,
    const float* __restrict__ Wp, const float* __restrict__ Bp,
    float* __restrict__ out)
{
    __shared__ unsigned short y[64][256];            // LN output, bf16 bits
    __shared__ unsigned short q[64][34], kk[64][34], v[64][34];
    __shared__ float s[64][65];
    int w = blockIdx.x, p = w & 31, t = threadIdx.x;
    int wave = t >> 6, lane = t & 63;
    size_t base = (size_t)w * 16384;                 // w*64*256

    // ---- LN over D=256 per row; also out = x (fp32 residual init) ----
    for (int it = 0; it < 16; ++it) {
        int r = it * 4 + wave;
        float vals[4]; float sum = 0.f, sq = 0.f;
#pragma unroll
        for (int k2 = 0; k2 < 4; ++k2) {
            float vv = x[base + (size_t)r * 256 + lane + 64 * k2];
            vals[k2] = vv; sum += vv; sq += vv * vv;
        }
        for (int o = 32; o > 0; o >>= 1) { sum += __shfl_xor(sum, o); sq += __shfl_xor(sq, o); }
        float mu = sum * (1.f / 256.f);
        float var = sq * (1.f / 256.f) - mu * mu;
        float rstd = rsqrtf(var + 1e-5f);
#pragma unroll
        for (int k2 = 0; k2 < 4; ++k2) {
            int c = lane + 64 * k2;
            y[r][c] = f2u((vals[k2] - mu) * rstd * g1[c] + be1[c]);
            out[base + (size_t)r * 256 + c] = vals[k2];
        }
    }
    __syncthreads();

    int n = t >> 2, c0 = (t & 3) * 64;   // epilogue/proj ownership: row n, 64 cols
    float oacc[64];
#pragma unroll
    for (int cc = 0; cc < 64; ++cc) oacc[cc] = Bp[c0 + cc];

    for (int h = 0; h < 8; ++h) {
        // ---- qkv for head h: 64 x (3x32) outputs ----
        for (int j = 0; j < 24; ++j) {
            int oi = j * 256 + t;
            int nn = oi / 96, c96 = oi % 96;
            int which = c96 >> 5, d = c96 & 31;
            int gcol = which * 256 + h * 32 + d;     // qkv col layout: s*256 + h*32 + d
            float acc = Bqkv[gcol];
            for (int dd = 0; dd < 256; ++dd)
                acc += u2f(y[nn][dd]) * Wqkv[(size_t)dd * 768 + gcol];
            unsigned short ub = f2u(acc);
            if (which == 0) q[nn][d] = ub;
            else if (which == 1) kk[nn][d] = ub;
            else v[nn][d] = ub;
        }
        __syncthreads();
        // ---- scores s[i][j] = q.k * hd^-0.5 + log(adj+1e-6) ----
        for (int j = 0; j < 16; ++j) {
            int idx = j * 256 + t;
            int i = idx >> 6, jj = idx & 63;
            float a = 0.f;
#pragma unroll
            for (int d = 0; d < 32; ++d) a += u2f(q[i][d]) * u2f(kk[jj][d]);
            s[i][jj] = a * 0.17677669529663689f + logf(adj[i * 64 + jj] + 1e-6f);
        }
        __syncthreads();
        // ---- softmax, 4 lanes per row ----
        {
            int r = t >> 2, sub = t & 3;
            float mx = -1e30f;
            for (int jj = sub; jj < 64; jj += 4) mx = fmaxf(mx, s[r][jj]);
            mx = fmaxf(mx, __shfl_xor(mx, 1)); mx = fmaxf(mx, __shfl_xor(mx, 2));
            float sum = 0.f;
            for (int jj = sub; jj < 64; jj += 4) { float e = __expf(s[r][jj] - mx); s[r][jj] = e; sum += e; }
            sum += __shfl_xor(sum, 1); sum += __shfl_xor(sum, 2);
            float inv = 1.f / sum;
            for (int jj = sub; jj < 64; jj += 4) s[r][jj] *= inv;
        }
        __syncthreads();
        // ---- o = softmax @ v, stored into q (q dead after scores) ----
        for (int j = 0; j < 8; ++j) {
            int idx = j * 256 + t;
            int i = idx >> 5, d = idx & 31;
            float a = 0.f;
            for (int jj = 0; jj < 64; ++jj) a += s[i][jj] * u2f(v[jj][d]);
            q[i][d] = f2u(a);
        }
        __syncthreads();
        // ---- proj accumulate: oacc += o_h @ Wp[h*32:(h+1)*32, :] ----
        for (int d = 0; d < 32; ++d) {
            float ov = u2f(q[n][d]);
            const float* wrow = Wp + (size_t)(h * 32 + d) * 256 + c0;
#pragma unroll
            for (int cc = 0; cc < 64; ++cc) oacc[cc] += ov * wrow[cc];
        }
        __syncthreads();
    }
    // ---- epilogue: out += oacc * mask[p][n]  (fp32 RMW) ----
    float mv = mask[p * 64 + n];
    for (int cc = 0; cc < 64; ++cc) {
        size_t idx = base + (size_t)n * 256 + c0 + cc;
        out[idx] += oacc[cc] * mv;
    }
}

// ===================== Kernel B: LN2 + MLP residual =========================
__global__ __launch_bounds__(256) void mlp_block_k(
    const float* __restrict__ mask,
    const float* __restrict__ g2, const float* __restrict__ be2,
    const float* __restrict__ W1, const float* __restrict__ B1,
    const float* __restrict__ W2, const float* __restrict__ B2,
    float* __restrict__ out)
{
    __shared__ unsigned short y[64][256];
    __shared__ float ht[64][65];
    int w = blockIdx.x, p = w & 31, t = threadIdx.x;
    int wave = t >> 6, lane = t & 63;
    size_t base = (size_t)w * 16384;
    // ---- LN2 from out (= x5 after attention, fp32) ----
    for (int it = 0; it < 16; ++it) {
        int r = it * 4 + wave;
        float vals[4]; float sum = 0.f, sq = 0.f;
#pragma unroll
        for (int k2 = 0; k2 < 4; ++k2) {
            float vv = out[base + (size_t)r * 256 + lane + 64 * k2];
            vals[k2] = vv; sum += vv; sq += vv * vv;
        }
        for (int o = 32; o > 0; o >>= 1) { sum += __shfl_xor(sum, o); sq += __shfl_xor(sq, o); }
        float mu = sum * (1.f / 256.f);
        float var = sq * (1.f / 256.f) - mu * mu;
        float rstd = rsqrtf(var + 1e-5f);
#pragma unroll
        for (int k2 = 0; k2 < 4; ++k2) {
            int c = lane + 64 * k2;
            y[r][c] = f2u((vals[k2] - mu) * rstd * g2[c] + be2[c]);
        }
    }
    __syncthreads();
    int n = t >> 2, c0 = (t & 3) * 64;
    float oacc[64];
#pragma unroll
    for (int cc = 0; cc < 64; ++cc) oacc[cc] = B2[c0 + cc];
    for (int tile = 0; tile < 16; ++tile) {
        // ---- fc1 tile (64 cols) + gelu ----
        for (int j = 0; j < 16; ++j) {
            int oi = j * 256 + t;
            int nn = oi >> 6, jj = oi & 63;
            int col = tile * 64 + jj;
            float acc = B1[col];
            for (int dd = 0; dd < 256; ++dd)
                acc += u2f(y[nn][dd]) * W1[(size_t)dd * 1024 + col];
            ht[nn][jj] = gelu_exact(acc);
        }
        __syncthreads();
        // ---- fc2 accumulate ----
        for (int jj = 0; jj < 64; ++jj) {
            float hv = ht[n][jj];
            const float* wrow = W2 + (size_t)(tile * 64 + jj) * 256 + c0;
#pragma unroll
            for (int cc = 0; cc < 64; ++cc) oacc[cc] += hv * wrow[cc];
        }
        __syncthreads();
    }
    float mv = mask[p * 64 + n];
    for (int cc = 0; cc < 64; ++cc) {
        size_t idx = base + (size_t)n * 256 + c0 + cc;
        out[idx] += oacc[cc] * mv;
    }
}

// ===================== Kernel C: pooled z-branch ============================
// One block per bt (32 blocks). Touches only its own bt's windows.
__global__ __launch_bounds__(256) void zbranch_k(
    const float* __restrict__ mask,
    const float* __restrict__ gb, const float* __restrict__ bb,
    const float* __restrict__ Wqkv, const float* __restrict__ Bqkv,
    const float* __restrict__ Wp, const float* __restrict__ Bp,
    const float* __restrict__ W1, const float* __restrict__ B1,
    const float* __restrict__ W2, const float* __restrict__ B2,
    float* __restrict__ out)
{
    __shared__ float zs[32][257];                 // pooled z -> LN'd z -> attn out
    __shared__ float q[32][33], kk[32][33], v[32][33];
    __shared__ float s[32][65];                   // scores; reused as fc1 htile
    int bt = blockIdx.x, t = threadIdx.x;
    int wave = t >> 6, lane = t & 63;
    size_t base = (size_t)bt * 524288;            // bt*32*64*256

    // ---- masked mean-pool over N=64 ----
    for (int j = 0; j < 32; ++j) {
        int oi = j * 256 + t;
        int p = oi >> 8, c = oi & 255;
        float msum = 0.f, acc = 0.f;
        for (int nn = 0; nn < 64; ++nn) {
            float mv = mask[p * 64 + nn];
            msum += mv;
            acc += mv * out[base + (size_t)(p * 64 + nn) * 256 + c];
        }
        zs[p][c] = acc / fmaxf(msum, 1.0f);
    }
    __syncthreads();
    // ---- LN over D=256, rows 32, in place ----
    for (int it = 0; it < 8; ++it) {
        int r = it * 4 + wave;
        float vals[4]; float sum = 0.f, sq = 0.f;
#pragma unroll
        for (int k2 = 0; k2 < 4; ++k2) {
            float vv = zs[r][lane + 64 * k2];
            vals[k2] = vv; sum += vv; sq += vv * vv;
        }
        for (int o = 32; o > 0; o >>= 1) { sum += __shfl_xor(sum, o); sq += __shfl_xor(sq, o); }
        float mu = sum * (1.f / 256.f);
        float var = sq * (1.f / 256.f) - mu * mu;
        float rstd = rsqrtf(var + 1e-5f);
#pragma unroll
        for (int k2 = 0; k2 < 4; ++k2) {
            int c = lane + 64 * k2;
            zs[r][c] = (vals[k2] - mu) * rstd * gb[c] + bb[c];
        }
    }
    __syncthreads();

    // ---- attention (32 tokens, 8 heads, no bias) ----
    int n8 = t >> 3, c08 = (t & 7) * 32;          // ownership: row n8, 32 cols
    float oacc[32];
#pragma unroll
    for (int cc = 0; cc < 32; ++cc) oacc[cc] = Bp[c08 + cc];
    for (int h = 0; h < 8; ++h) {
        for (int j = 0; j < 12; ++j) {
            int oi = j * 256 + t;
            int nn = oi / 96, c96 = oi % 96;
            int which = c96 >> 5, d = c96 & 31;
            int gcol = which * 256 + h * 32 + d;
            float acc = Bqkv[gcol];
            for (int dd = 0; dd < 256; ++dd)
                acc += zs[nn][dd] * Wqkv[(size_t)dd * 768 + gcol];
            if (which == 0) q[nn][d] = acc;
            else if (which == 1) kk[nn][d] = acc;
            else v[nn][d] = acc;
        }
        __syncthreads();
        for (int j = 0; j < 4; ++j) {
            int idx = j * 256 + t;
            int i = idx >> 5, jj = idx & 31;
            float a = 0.f;
#pragma unroll
            for (int d = 0; d < 32; ++d) a += q[i][d] * kk[jj][d];
            s[i][jj] = a * 0.17677669529663689f;
        }
        __syncthreads();
        {
            int r = t >> 3, sub = t & 7;
            float mx = -1e30f;
            for (int jj = sub; jj < 32; jj += 8) mx = fmaxf(mx, s[r][jj]);
            for (int o = 1; o < 8; o <<= 1) mx = fmaxf(mx, __shfl_xor(mx, o));
            float sum = 0.f;
            for (int jj = sub; jj < 32; jj += 8) { float e = __expf(s[r][jj] - mx); s[r][jj] = e; sum += e; }
            for (int o = 1; o < 8; o <<= 1) sum += __shfl_xor(sum, o);
            float inv = 1.f / sum;
            for (int jj = sub; jj < 32; jj += 8) s[r][jj] *= inv;
        }
        __syncthreads();
        {
            float od[32];
#pragma unroll
            for (int d = 0; d < 32; ++d) {
                float a = 0.f;
                for (int jj = 0; jj < 32; ++jj) a += s[n8][jj] * v[jj][d];
                od[d] = a;
            }
            for (int d = 0; d < 32; ++d) {
                const float* wrow = Wp + (size_t)(h * 32 + d) * 256 + c08;
                float ov = od[d];
#pragma unroll
                for (int cc = 0; cc < 32; ++cc) oacc[cc] += ov * wrow[cc];
            }
        }
        __syncthreads();
    }
    // ---- z = attention output (no residual) -> zs ----
    for (int cc = 0; cc < 32; ++cc) zs[n8][c08 + cc] = oacc[cc];
    __syncthreads();
    // ---- MLP (no residual) ----
    float oacc2[32];
#pragma unroll
    for (int cc = 0; cc < 32; ++cc) oacc2[cc] = B2[c08 + cc];
    for (int tile = 0; tile < 16; ++tile) {
        for (int j = 0; j < 8; ++j) {
            int oi = j * 256 + t;
            int nn = oi >> 6, jj = oi & 63;
            int col = tile * 64 + jj;
            float acc = B1[col];
            for (int dd = 0; dd < 256; ++dd)
                acc += zs[nn][dd] * W1[(size_t)dd * 1024 + col];
            s[nn][jj] = gelu_exact(acc);          // s reused as htile
        }
        __syncthreads();
        for (int jj = 0; jj < 64; ++jj) {
            float hv = s[n8][jj];
            const float* wrow = W2 + (size_t)(tile * 64 + jj) * 256 + c08;
#pragma unroll
            for (int cc = 0; cc < 32; ++cc) oacc2[cc] += hv * wrow[cc];
        }
        __syncthreads();
    }
    // ---- broadcast add over N (fp32 RMW) ----
    for (int nn = 0; nn < 64; ++nn) {
        size_t rowb = base + (size_t)(n8 * 64 + nn) * 256 + c08;
        for (int cc = 0; cc < 32; ++cc)
            out[rowb + cc] += oacc2[cc];
    }
}

extern "C" void kernel_launch(void* const* d_in, const int* in_sizes, int n_in,
                              void* d_out, int out_size, void* d_ws, size_t ws_size,
                              hipStream_t stream) {
    (void)in_sizes; (void)n_in; (void)out_size; (void)d_ws; (void)ws_size;
    const float* x        = (const float*)d_in[0];
    const float* mask     = (const float*)d_in[1];
    const float* adj      = (const float*)d_in[2];
    const float* dn1_g    = (const float*)d_in[3];
    const float* dn1_b    = (const float*)d_in[4];
    const float* dn2_g    = (const float*)d_in[5];
    const float* dn2_b    = (const float*)d_in[6];
    const float* bn1_g    = (const float*)d_in[7];
    const float* bn1_b    = (const float*)d_in[8];
    const float* d_qkv_w  = (const float*)d_in[9];
    const float* d_qkv_b  = (const float*)d_in[10];
    const float* d_proj_w = (const float*)d_in[11];
    const float* d_proj_b = (const float*)d_in[12];
    const float* d_fc1_w  = (const float*)d_in[13];
    const float* d_fc1_b  = (const float*)d_in[14];
    const float* d_fc2_w  = (const float*)d_in[15];
    const float* d_fc2_b  = (const float*)d_in[16];
    const float* b_qkv_w  = (const float*)d_in[17];
    const float* b_qkv_b  = (const float*)d_in[18];
    const float* b_proj_w = (const float*)d_in[19];
    const float* b_proj_b = (const float*)d_in[20];
    const float* b_fc1_w  = (const float*)d_in[21];
    const float* b_fc1_b  = (const float*)d_in[22];
    const float* b_fc2_w  = (const float*)d_in[23];
    const float* b_fc2_b  = (const float*)d_in[24];
    float* out = (float*)d_out;   // reference output dtype is float32

    attn_block_k<<<1024, 256, 0, stream>>>(x, mask, adj, dn1_g, dn1_b,
                                           d_qkv_w, d_qkv_b, d_proj_w, d_proj_b, out);
    mlp_block_k<<<1024, 256, 0, stream>>>(mask, dn2_g, dn2_b,
                                          d_fc1_w, d_fc1_b, d_fc2_w, d_fc2_b, out);
    zbranch_k<<<32, 256, 0, stream>>>(mask, bn1_g, bn1_b,
                                      b_qkv_w, b_qkv_b, b_proj_w, b_proj_b,
                                      b_fc1_w, b_fc1_b, b_fc2_w, b_fc2_b, out);
}